// Round 4
// baseline (186.299 us; speedup 1.0000x reference)
//
#include <hip/hip_runtime.h>
#include <math.h>

// Density loss: B=8, N=2048, C=3, K=16 (self-distance 0 included).
// R4: 512-thread blocks (8 waves), 4 points/wave, 4 blocks/CU co-resident.
//   Staged pts carry |x|^2 in .w; track d~ = |xj|^2 - 2 xi.xj (ordering
//   invariant per point), add 16*|xi|^2 at the end. Per lane per point:
//   sorted 4-slot min-list. thr = 16th smallest lane-min (bitonic64 x4
//   interleaved). Counts via ballot/popcount (scalar pipe). sum16 = qualifier
//   sum - (cnt-16) largest (butterfly-max rounds). Overflow (lane holds >=4
//   qualifiers, ~1.2%/pt) -> exact streaming extraction (proven R3 path).
// Kernel 2: 1 block reduces 1024 block-partials -> scalar MSE.

#define NPTS 2048

// Exact fallback: 16 rounds of global min-extraction with lexicographic
// (value, candidate-index) keys; re-reads LDS each round. True distances.
__device__ __attribute__((noinline)) float exact_stream(
    const float4* __restrict__ pts, float px, float py, float pz, int lane) {
  float lastV = -INFINITY;
  int lastI = -1;
  float s = 0.f;
  for (int r = 0; r < 16; ++r) {
    float bv = INFINITY;
    int bi = 0x7fffffff;
    #pragma unroll
    for (int m = 0; m < 32; ++m) {
      float4 c = pts[lane + (m << 6)];
      float dx = px - c.x, dy = py - c.y, dz = pz - c.z;
      float d = fmaf(dz, dz, fmaf(dy, dy, dx * dx));
      int idx = (m << 6) | lane;
      bool gt = (d > lastV) || (d == lastV && idx > lastI);
      bool better = gt && ((d < bv) || (d == bv && idx < bi));
      bv = better ? d : bv;
      bi = better ? idx : bi;
    }
    #pragma unroll
    for (int ofs = 1; ofs < 64; ofs <<= 1) {
      float ov = __shfl_xor(bv, ofs);
      int oi = __shfl_xor(bi, ofs);
      bool take = (ov < bv) || (ov == bv && oi < bi);
      bv = take ? ov : bv;
      bi = take ? oi : bi;
    }
    s += bv;
    lastV = bv;
    lastI = bi;
  }
  return s;
}

__global__ __launch_bounds__(512, 8) void knn_kernel(
    const float* __restrict__ seed, const float* __restrict__ gt,
    float* __restrict__ out_partial) {
  __shared__ float4 pts[NPTS];  // 32 KB
  __shared__ float wsum[8];

  const int bid = blockIdx.x;    // 1024 = 2*8*64
  const int t = bid >> 9;        // tensor
  const int b = (bid >> 6) & 7;  // batch
  const int g = bid & 63;        // group of 32 points
  const float* base = (t == 0 ? seed : gt) + b * (NPTS * 3);
  const int tid = threadIdx.x;

  // Stage 2048 points; consecutive-lane b128 writes (conflict-free).
  #pragma unroll
  for (int r = 0; r < 4; ++r) {
    int p = tid + (r << 9);
    float x = base[3 * p], y = base[3 * p + 1], z = base[3 * p + 2];
    float w = fmaf(z, z, fmaf(y, y, x * x));  // |xj|^2
    pts[p] = make_float4(x, y, z, w);
  }
  __syncthreads();

  const int wave = tid >> 6, lane = tid & 63;
  const int i0 = (g << 5) + (wave << 2);

  float px[4], py[4], pz[4];
  #pragma unroll
  for (int j = 0; j < 4; ++j) {
    float4 q = pts[i0 + j];
    px[j] = q.x; py[j] = q.y; pz[j] = q.z;
  }

  // Sorted 4 smallest d~ per lane per point (ascending s0..s3).
  float s0[4], s1[4], s2[4], s3[4];
  #pragma unroll
  for (int j = 0; j < 4; ++j) s0[j] = s1[j] = s2[j] = s3[j] = INFINITY;

  #pragma unroll 8
  for (int m = 0; m < 32; ++m) {
    float4 c = pts[lane + (m << 6)];
    #pragma unroll
    for (int j = 0; j < 4; ++j) {
      float dot = fmaf(pz[j], c.z, fmaf(py[j], c.y, px[j] * c.x));
      float d = fmaf(-2.f, dot, c.w);  // d~ = |xj|^2 - 2 xi.xj
      float u;
      u = fminf(s0[j], d); d = fmaxf(s0[j], d); s0[j] = u;
      u = fminf(s1[j], d); d = fmaxf(s1[j], d); s1[j] = u;
      u = fminf(s2[j], d); d = fmaxf(s2[j], d); s2[j] = u;
      s3[j] = fminf(s3[j], d);
    }
  }

  // thr[j] = 16th smallest lane-min via interleaved bitonic64 over s0.
  float v0 = s0[0], v1 = s0[1], v2 = s0[2], v3 = s0[3];
  #pragma unroll
  for (int k = 2; k <= 64; k <<= 1) {
    #pragma unroll
    for (int j = k >> 1; j > 0; j >>= 1) {
      bool keepmin = ((lane & j) == 0) != ((lane & k) != 0);
      float p0 = __shfl_xor(v0, j), p1 = __shfl_xor(v1, j);
      float p2 = __shfl_xor(v2, j), p3 = __shfl_xor(v3, j);
      v0 = keepmin ? fminf(v0, p0) : fmaxf(v0, p0);
      v1 = keepmin ? fminf(v1, p1) : fmaxf(v1, p1);
      v2 = keepmin ? fminf(v2, p2) : fmaxf(v2, p2);
      v3 = keepmin ? fminf(v3, p3) : fmaxf(v3, p3);
    }
  }
  const float thr[4] = {__shfl(v0, 15), __shfl(v1, 15), __shfl(v2, 15),
                        __shfl(v3, 15)};

  // Qualifier counts via ballot/popcount (scalar pipe); sums via butterfly.
  int cnt[4];
  unsigned long long bad[4];
  float sq[4];
  #pragma unroll
  for (int j = 0; j < 4; ++j) {
    bool q0 = s0[j] <= thr[j], q1 = s1[j] <= thr[j];
    bool q2 = s2[j] <= thr[j], q3 = s3[j] <= thr[j];
    unsigned long long b3 = __ballot(q3);
    bad[j] = b3;  // lane may hold >= 4 qualifiers -> possible drop
    cnt[j] = __popcll(__ballot(q0)) + __popcll(__ballot(q1)) +
             __popcll(__ballot(q2)) + __popcll(b3);
    sq[j] = (q0 ? s0[j] : 0.f) + (q1 ? s1[j] : 0.f) +
            (q2 ? s2[j] : 0.f) + (q3 ? s3[j] : 0.f);
  }
  #pragma unroll
  for (int ofs = 1; ofs < 64; ofs <<= 1) {
    #pragma unroll
    for (int j = 0; j < 4; ++j) sq[j] += __shfl_xor(sq[j], ofs);
  }

  float out[4];
  #pragma unroll
  for (int j = 0; j < 4; ++j) {
    if (bad[j] != 0ull || cnt[j] > 48) {  // wave-uniform, rare
      out[j] = exact_stream(pts, px[j], py[j], pz[j], lane);
    } else {
      float a0 = s0[j], a1 = s1[j], a2 = s2[j], a3 = s3[j];
      const float T = thr[j];
      float S = sq[j];
      const int r = cnt[j] - 16;  // wave-uniform, >= 0
      for (int q = 0; q < r; ++q) {
        float lm = -INFINITY;
        lm = (a0 <= T) ? fmaxf(lm, a0) : lm;
        lm = (a1 <= T) ? fmaxf(lm, a1) : lm;
        lm = (a2 <= T) ? fmaxf(lm, a2) : lm;
        lm = (a3 <= T) ? fmaxf(lm, a3) : lm;
        float bv = lm;
        #pragma unroll
        for (int ofs = 1; ofs < 64; ofs <<= 1) bv = fmaxf(bv, __shfl_xor(bv, ofs));
        S -= bv;
        int owner = __builtin_ctzll(__ballot(lm == bv));
        if (lane == owner) {  // retire one instance
          if (a3 == bv) a3 = INFINITY;
          else if (a2 == bv) a2 = INFINITY;
          else if (a1 == bv) a1 = INFINITY;
          else a0 = INFINITY;
        }
      }
      float sqi = fmaf(pz[j], pz[j], fmaf(py[j], py[j], px[j] * px[j]));
      out[j] = S + 16.f * sqi;  // undo the per-point additive shift
    }
  }

  // Block partial: sum of this block's 32 point-sums.
  float wtot = out[0] + out[1] + out[2] + out[3];  // lane-uniform
  if (lane == 0) wsum[wave] = wtot;
  __syncthreads();
  if (wave == 0) {
    float v = (lane < 8) ? wsum[lane] : 0.f;
    #pragma unroll
    for (int ofs = 1; ofs < 64; ofs <<= 1) v += __shfl_xor(v, ofs);
    if (lane == 0) out_partial[bid] = v;
  }
}

__global__ __launch_bounds__(1024) void final_kernel(
    const float* __restrict__ part, float* __restrict__ out) {
  __shared__ float acc[16];
  const int tid = threadIdx.x;  // 1024
  const int wave = tid >> 6, lane = tid & 63;
  float v = part[tid];  // wave w covers segment (t*8+b) == w
  #pragma unroll
  for (int ofs = 1; ofs < 64; ofs <<= 1) v += __shfl_xor(v, ofs);
  if (lane == 0) acc[wave] = v;
  __syncthreads();
  if (tid == 0) {
    const float scale = 1.f / (2048.f * 16.f);
    float a = 0.f;
    #pragma unroll
    for (int bb = 0; bb < 8; ++bb) {
      float diff = (acc[bb] - acc[8 + bb]) * scale;
      a += diff * diff;
    }
    out[0] = a * 0.125f;
  }
}

extern "C" void kernel_launch(void* const* d_in, const int* in_sizes, int n_in,
                              void* d_out, int out_size, void* d_ws, size_t ws_size,
                              hipStream_t stream) {
  const float* seed = (const float*)d_in[0];
  const float* gt = (const float*)d_in[1];
  float* out = (float*)d_out;
  float* ws = (float*)d_ws;  // 1024 floats used

  knn_kernel<<<1024, 512, 0, stream>>>(seed, gt, ws);
  final_kernel<<<1, 1024, 0, stream>>>(ws, out);
}